// Round 4
// baseline (612.320 us; speedup 1.0000x reference)
//
#include <hip/hip_runtime.h>

// RunningCenters R10: sort-free direct accumulation.
// R7(5-kernel sort)==R9(3-kernel sort)==348us proved the sort-then-gather
// STRUCTURE is the plateau (~150us scatter + ~150us gather vs ~42us traffic
// roofline). Replace with one streaming pass: LDS fp32 atomics (ds_add_f32)
// accumulate per-class partial sums, D split into 4 chunks of 32 so
// sums[1000][32]=128KB fits LDS. 64 point-partitions x 4 chunks = 256
// blocks; x read once, fully coalesced, no index gather, no scattered
// writes. Partials (32MB) reduced + CMA in a second kernel.

constexpr int C = 1000;
constexpr int D = 128;
constexpr int PARTS = 64;   // point partitions
constexpr int CHUNKS = 4;   // D chunks
constexpr int DC = 32;      // D / CHUNKS
constexpr int AT = 1024;    // accum threads (16 waves)
constexpr int NW = AT / 64; // waves per block
constexpr int RT = 128;     // reduce threads (one per d)

typedef float f4 __attribute__((ext_vector_type(4)));

// ws layout (poison-safe: both regions fully written before read):
// partial f32[PARTS*CHUNKS][C*DC]  @ 0         (32.768 MB)
// histp   u32[C*PARTS]             @ 33 MiB    (256 KB), layout c*PARTS+p

__global__ __launch_bounds__(AT) void accum_kernel(
    const float* __restrict__ x, const int* __restrict__ y,
    float* __restrict__ partial, unsigned int* __restrict__ histp, int N) {
  const int part = blockIdx.x >> 2;
  const int chunk = blockIdx.x & 3;
  const int d0 = chunk * DC;

  __shared__ float sums[C * DC];        // 128000 B
  __shared__ unsigned int hist[C];      //   4000 B
  for (int t = threadIdx.x; t < C * DC; t += AT) sums[t] = 0.f;
  if (chunk == 0)
    for (int t = threadIdx.x; t < C; t += AT) hist[t] = 0u;
  __syncthreads();

  const int per = (N + PARTS - 1) / PARTS;
  const int beg = part * per;
  const int end = min(beg + per, N);
  const int wave = threadIdx.x >> 6;
  const int lane = threadIdx.x & 63;
  const int half = lane >> 5;  // which point of the wave's pair
  const int dl = lane & 31;    // which float of the 32-wide d-chunk

  const int stride = NW * 2;  // 32 points per block-step
  int i = beg + wave * 2 + half;
  // main loop, unroll 8: 8 y loads + 8 x loads all independent -> 16 loads
  // in flight per wave before the first ds_add needs them.
  for (; i + 7 * stride < end; i += 8 * stride) {
#pragma unroll
    for (int u = 0; u < 8; ++u) {
      const int ii = i + u * stride;
      const int c = y[ii];                               // broadcast in half
      const float v = x[(size_t)ii * D + d0 + dl];       // 128B coalesced
      atomicAdd(&sums[c * DC + dl], v);                  // ds_add_f32, 2-way
      if (chunk == 0 && dl == 0) atomicAdd(&hist[c], 1u);
    }
  }
  for (; i < end; i += stride) {
    const int c = y[i];
    const float v = x[(size_t)i * D + d0 + dl];
    atomicAdd(&sums[c * DC + dl], v);
    if (chunk == 0 && dl == 0) atomicAdd(&hist[c], 1u);
  }

  __syncthreads();
  // dump partial: contiguous 128KB, f4-coalesced
  f4* dst = (f4*)(partial + (size_t)blockIdx.x * (C * DC));
  const f4* src = (const f4*)sums;
  for (int t = threadIdx.x; t < C * DC / 4; t += AT) dst[t] = src[t];
  if (chunk == 0)
    for (int t = threadIdx.x; t < C; t += AT)
      histp[t * PARTS + part] = hist[t];
}

__global__ __launch_bounds__(RT) void reduce_kernel(
    const float* __restrict__ partial, const unsigned int* __restrict__ histp,
    const float* __restrict__ centers, const float* __restrict__ counter,
    float* __restrict__ out) {
  const int c = blockIdx.x;
  const int d = threadIdx.x;
  const int chunk = d >> 5;
  const int dd = d & 31;

  __shared__ unsigned int nsh;
  if (d < 64) {  // wave 0: count = sum of 64 partition hists (coalesced 256B)
    unsigned int v = histp[c * PARTS + d];
#pragma unroll
    for (int off = 32; off; off >>= 1) v += __shfl_down(v, off, 64);
    if (d == 0) nsh = v;
  }
  __syncthreads();
  const int n = (int)nsh;

  const size_t base = (size_t)chunk * (C * DC) + c * DC + dd;
  float s = 0.f;
#pragma unroll 8
  for (int p = 0; p < PARTS; ++p)
    s += partial[base + (size_t)p * (CHUNKS * C * DC)];

  const float cen = centers[c * D + d];
  float o;
  if (n > 0) {
    const float k = counter[0];
    o = (s / (float)n + cen * k) / (k + 1.f);
  } else {
    o = cen;
  }
  out[c * D + d] = o;
}

extern "C" void kernel_launch(void* const* d_in, const int* in_sizes, int n_in,
                              void* d_out, int out_size, void* d_ws, size_t ws_size,
                              hipStream_t stream) {
  const float* x       = (const float*)d_in[0];
  const int* y         = (const int*)d_in[1];
  const float* centers = (const float*)d_in[2];
  const float* counter = (const float*)d_in[3];
  float* out = (float*)d_out;
  const int N = in_sizes[1];

  float* partial      = (float*)d_ws;
  unsigned int* histp = (unsigned int*)((char*)d_ws + (33u << 20));

  accum_kernel<<<dim3(PARTS * CHUNKS), dim3(AT), 0, stream>>>(x, y, partial,
                                                              histp, N);
  reduce_kernel<<<dim3(C), dim3(RT), 0, stream>>>(partial, histp, centers,
                                                  counter, out);
}

// Round 5
// 596.284 us; speedup vs baseline: 1.0269x; 1.0269x over previous
//
#include <hip/hip_runtime.h>

// RunningCenters R11: R10 structure + MLP rebuild of the accum inner loop.
// R10 diagnosis: VALUBusy 2.7%, VGPR=52 -> compiler serialized each
// load->ds_add chain (244 x ~900cy round-trips per wave = 360us).
// Fixes: (1) y staged in LDS per 2048-pt tile (off critical path),
// (2) histogram computed from ytile once per tile, not per point,
// (3) explicit 8-wide register double-buffer: next batch's 8 x-loads in
// flight during current batch's ds_adds (counted-vmcnt pipelining),
// (4) __hip_atomic_fetch_add relaxed/workgroup -> native ds_add_f32.

constexpr int C = 1000;
constexpr int D = 128;
constexpr int PARTS = 64;   // point partitions
constexpr int CHUNKS = 4;   // D chunks
constexpr int DC = 32;      // D / CHUNKS
constexpr int AT = 1024;    // accum threads (16 waves)
constexpr int NW = AT / 64; // waves per block = 16
constexpr int TP = 2048;    // points per staged tile (8 KB LDS)
constexpr int RT = 128;     // reduce threads (one per d)

typedef float f4 __attribute__((ext_vector_type(4)));

__device__ __forceinline__ void lds_fadd(float* p, float v) {
  __hip_atomic_fetch_add(p, v, __ATOMIC_RELAXED, __HIP_MEMORY_SCOPE_WORKGROUP);
}

// ws layout (poison-safe: both regions fully written before read):
// partial f32[PARTS*CHUNKS][C*DC]  @ 0         (32.768 MB)
// histp   u32[C*PARTS]             @ 33 MiB    (256 KB), layout c*PARTS+p

__global__ __launch_bounds__(AT) void accum_kernel(
    const float* __restrict__ x, const int* __restrict__ y,
    float* __restrict__ partial, unsigned int* __restrict__ histp, int N) {
  const int part = blockIdx.x >> 2;
  const int chunk = blockIdx.x & 3;
  const int d0 = chunk * DC;

  __shared__ float sums[C * DC];        // 128000 B
  __shared__ unsigned int hist[C];      //   4000 B
  __shared__ int ytile[TP];             //   8192 B  -> 140 KB total
  for (int t = threadIdx.x; t < C * DC; t += AT) sums[t] = 0.f;
  if (chunk == 0)
    for (int t = threadIdx.x; t < C; t += AT) hist[t] = 0u;

  const int per = (N + PARTS - 1) / PARTS;
  const int beg = part * per;
  const int end = min(beg + per, N);
  const int wave = threadIdx.x >> 6;
  const int lane = threadIdx.x & 63;
  const int half = lane >> 5;  // which point of the pair
  const int dl = lane & 31;    // which float of the 32-wide d-chunk

  const float* xp = x + d0 + dl;  // lane-invariant part folded once

  for (int t0 = beg; t0 < end; t0 += TP) {
    const int nt = min(TP, end - t0);
    __syncthreads();  // protects ytile reuse + sums init on first pass
    for (int t = threadIdx.x; t < nt; t += AT) ytile[t] = y[t0 + t];
    __syncthreads();
    if (chunk == 0) {  // histogram once per tile from LDS copy (u32 atomics)
      for (int t = threadIdx.x; t < nt; t += AT) atomicAdd(&hist[ytile[t]], 1u);
    }
    const int steps = nt >> 1;
    if (nt == TP) {
      // fast path: 1024 pair-steps, 64/wave = 8 batches of 8, pipelined.
      float va[8]; int ca[8];
#pragma unroll
      for (int u = 0; u < 8; ++u) {
        const int p = u * NW + wave;
        ca[u] = ytile[p * 2 + half];
        va[u] = xp[(size_t)(t0 + p * 2 + half) * D];
      }
      for (int b = 0; b < 8; ++b) {
        float vb[8]; int cb[8];
        if (b < 7) {
#pragma unroll
          for (int u = 0; u < 8; ++u) {
            const int p = ((b + 1) * 8 + u) * NW + wave;
            cb[u] = ytile[p * 2 + half];
            vb[u] = xp[(size_t)(t0 + p * 2 + half) * D];
          }
        }
#pragma unroll
        for (int u = 0; u < 8; ++u) lds_fadd(&sums[ca[u] * DC + dl], va[u]);
        if (b < 7) {
#pragma unroll
          for (int u = 0; u < 8; ++u) { va[u] = vb[u]; ca[u] = cb[u]; }
        }
      }
    } else {
      for (int p = wave; p < steps; p += NW) {
        const int c = ytile[p * 2 + half];
        lds_fadd(&sums[c * DC + dl], xp[(size_t)(t0 + p * 2 + half) * D]);
      }
      if ((nt & 1) && wave == 0 && half == 0) {  // odd tail point, lanes 0-31
        const int c = ytile[nt - 1];
        lds_fadd(&sums[c * DC + dl], xp[(size_t)(t0 + nt - 1) * D]);
      }
    }
  }

  __syncthreads();
  // dump partial: contiguous 128KB, f4-coalesced
  f4* dst = (f4*)(partial + (size_t)blockIdx.x * (C * DC));
  const f4* src = (const f4*)sums;
  for (int t = threadIdx.x; t < C * DC / 4; t += AT) dst[t] = src[t];
  if (chunk == 0)
    for (int t = threadIdx.x; t < C; t += AT)
      histp[t * PARTS + part] = hist[t];
}

__global__ __launch_bounds__(RT) void reduce_kernel(
    const float* __restrict__ partial, const unsigned int* __restrict__ histp,
    const float* __restrict__ centers, const float* __restrict__ counter,
    float* __restrict__ out) {
  const int c = blockIdx.x;
  const int d = threadIdx.x;
  const int chunk = d >> 5;
  const int dd = d & 31;

  __shared__ unsigned int nsh;
  if (d < 64) {  // wave 0: count = sum of 64 partition hists (coalesced 256B)
    unsigned int v = histp[c * PARTS + d];
#pragma unroll
    for (int off = 32; off; off >>= 1) v += __shfl_down(v, off, 64);
    if (d == 0) nsh = v;
  }
  __syncthreads();
  const int n = (int)nsh;

  const size_t base = (size_t)chunk * (C * DC) + c * DC + dd;
  float s = 0.f;
#pragma unroll 8
  for (int p = 0; p < PARTS; ++p)
    s += partial[base + (size_t)p * (CHUNKS * C * DC)];

  const float cen = centers[c * D + d];
  float o;
  if (n > 0) {
    const float k = counter[0];
    o = (s / (float)n + cen * k) / (k + 1.f);
  } else {
    o = cen;
  }
  out[c * D + d] = o;
}

extern "C" void kernel_launch(void* const* d_in, const int* in_sizes, int n_in,
                              void* d_out, int out_size, void* d_ws, size_t ws_size,
                              hipStream_t stream) {
  const float* x       = (const float*)d_in[0];
  const int* y         = (const int*)d_in[1];
  const float* centers = (const float*)d_in[2];
  const float* counter = (const float*)d_in[3];
  float* out = (float*)d_out;
  const int N = in_sizes[1];

  float* partial      = (float*)d_ws;
  unsigned int* histp = (unsigned int*)((char*)d_ws + (33u << 20));

  accum_kernel<<<dim3(PARTS * CHUNKS), dim3(AT), 0, stream>>>(x, y, partial,
                                                              histp, N);
  reduce_kernel<<<dim3(C), dim3(RT), 0, stream>>>(partial, histp, centers,
                                                  counter, out);
}